// Round 14
// baseline (116.502 us; speedup 1.0000x reference)
//
#include <hip/hip_runtime.h>
#include <hip/hip_fp16.h>
#include <stdint.h>

typedef _Float16 half_t;
typedef _Float16 hf2 __attribute__((ext_vector_type(2)));
typedef _Float16 hf4 __attribute__((ext_vector_type(4)));
typedef _Float16 hf8 __attribute__((ext_vector_type(8)));
typedef float f32x4 __attribute__((ext_vector_type(4)));
typedef float f32x16 __attribute__((ext_vector_type(16)));
typedef unsigned uint2_t __attribute__((ext_vector_type(2)));

#define LOG2E 1.4426950408889634f

// async global->LDS, 16B per lane; LDS dest must be wave-uniform base (+lane*16 by HW)
__device__ __forceinline__ void gload16(const void* g, void* l) {
  __builtin_amdgcn_global_load_lds(
      (const __attribute__((address_space(1))) unsigned int*)g,
      (__attribute__((address_space(3))) unsigned int*)l, 16, 0, 0);
}

__device__ __forceinline__ unsigned packrtz(float a, float b) {
  auto h = __builtin_amdgcn_cvt_pkrtz(a, b);
  union { decltype(h) h2; unsigned u; } c;
  c.h2 = h;
  return c.u;
}

__device__ __forceinline__ float exp2fast(float x) {
#if __has_builtin(__builtin_amdgcn_exp2f)
  return __builtin_amdgcn_exp2f(x);
#else
  return exp2f(x);
#endif
}

__device__ __forceinline__ float psum2(unsigned pw, hf2 ones, float acc) {
#if __has_builtin(__builtin_amdgcn_fdot2)
  union { unsigned u; hf2 h; } c;
  c.u = pw;
  return __builtin_amdgcn_fdot2(c.h, ones, acc, false);
#else
  union { unsigned u; hf2 h; } c;
  c.u = pw;
  return acc + (float)c.h[0] + (float)c.h[1];
#endif
}

// ---------------- convert f32 -> f16 (x: 4194304 elems, then 4 weights of 1048576) ----
__global__ __launch_bounds__(256) void cvt_kernel(
    const float* __restrict__ x, const float* __restrict__ wq,
    const float* __restrict__ wk, const float* __restrict__ wv,
    const float* __restrict__ wo, half_t* __restrict__ xh,
    half_t* __restrict__ wh) {
  long e = ((long)blockIdx.x * 256 + threadIdx.x) * 16;
  const float* src;
  half_t* dst;
  if (e < 4194304L) {
    src = x + e;
    dst = xh + e;
  } else {
    long j = e - 4194304L;
    int w = (int)(j >> 20);
    long off = j & 1048575L;
    src = (w == 0 ? wq : w == 1 ? wk : w == 2 ? wv : wo) + off;
    dst = wh + ((long)w << 20) + off;
  }
  const float4* s4 = (const float4*)src;
  float4 f0 = s4[0], f1 = s4[1], f2 = s4[2], f3 = s4[3];
  hf8 o0 = {(half_t)f0.x, (half_t)f0.y, (half_t)f0.z, (half_t)f0.w,
            (half_t)f1.x, (half_t)f1.y, (half_t)f1.z, (half_t)f1.w};
  hf8 o1 = {(half_t)f2.x, (half_t)f2.y, (half_t)f2.z, (half_t)f2.w,
            (half_t)f3.x, (half_t)f3.y, (half_t)f3.z, (half_t)f3.w};
  *(hf8*)dst = o0;
  *(hf8*)(dst + 8) = o1;
}

// ---------------- GEMM core v7 (r13): 128x128, BK=64, 16x16x32, acc[4][4] -------------
// LDS 32KB: A[128][64]f16 at [0,16K), Bt[128][64] at [16K,32K). Row r at byte r*128
// (8 16B slots); slot s stored at s^(r&7); staging source pre-swizzled inverse.
// Fragment layouts (m89/m91): A/B operand row(col)=lane&15, k=(lane>>4)*8+j (16B);
// C/D: col=lane&15, row=(lane>>4)*4+reg. Bank-conflict-free (r13 PMC: 0).
__device__ __forceinline__ void gemm_core16(const half_t* __restrict__ A,
                                            const half_t* __restrict__ Bt,
                                            int m0, int n0, char* ldsb,
                                            f32x4 acc[4][4]) {
  const int tid = threadIdx.x;
  const int wid = tid >> 6;
  const int lane = tid & 63;
  const int l15 = lane & 15;
  const int l4 = lane >> 4;
  const int wm = wid >> 1, wn = wid & 1;

#pragma unroll
  for (int mi = 0; mi < 4; mi++)
#pragma unroll
    for (int ni = 0; ni < 4; ni++)
#pragma unroll
      for (int i = 0; i < 4; i++) acc[mi][ni][i] = 0.f;

  const int rowb = tid >> 3;
  const int c16 = (tid & 7) ^ (rowb & 7);
  int goA = (m0 + rowb) * 1024 + c16 * 8;
  int goB = (n0 + rowb) * 1024 + c16 * 8;

  const int l7 = lane & 7;
  const int arow = (wm * 64 + l15) * 128;
  const int brow = 16384 + (wn * 64 + l15) * 128;
  const int aks0 = arow + ((l4) ^ l7) * 16;
  const int aks1 = arow + ((4 + l4) ^ l7) * 16;
  const int bks0 = brow + ((l4) ^ l7) * 16;
  const int bks1 = brow + ((4 + l4) ^ l7) * 16;

  for (int kt = 0; kt < 16; ++kt) {
#pragma unroll
    for (int i = 0; i < 4; i++) {
      gload16(A + goA + i * 32768, ldsb + i * 4096 + wid * 1024);
      gload16(Bt + goB + i * 32768, ldsb + 16384 + i * 4096 + wid * 1024);
    }
    goA += 64;
    goB += 64;
    __syncthreads();
#pragma unroll
    for (int ks = 0; ks < 2; ks++) {
      const int ao = ks ? aks1 : aks0;
      const int bo = ks ? bks1 : bks0;
      hf8 af[4], bf[4];
#pragma unroll
      for (int mi = 0; mi < 4; mi++)
        af[mi] = *(const hf8*)(ldsb + ao + mi * 2048);
#pragma unroll
      for (int ni = 0; ni < 4; ni++)
        bf[ni] = *(const hf8*)(ldsb + bo + ni * 2048);
#pragma unroll
      for (int mi = 0; mi < 4; mi++)
#pragma unroll
        for (int ni = 0; ni < 4; ni++)
          acc[mi][ni] = __builtin_amdgcn_mfma_f32_16x16x32_f16(
              af[mi], bf[ni], acc[mi][ni], 0, 0, 0);
    }
    __syncthreads();
  }
}

// ---------------- QKV projection (z=0:Q, 1:K, 2:V) ------------------------------------
// Epilogue-noise L3 prefetch: the block's noise footprint is 4 contiguous 32KB chunks
// ({nr,ni} x {2 heads}; t-rows x 64 d are contiguous). 4 touch loads/thread (128B
// stride), kept alive via asm — they stream in under the ~36us GEMM loop so the
// epilogue's 67MB of cold f32 reads become L2/L3 hits (HBM is idle during the loop).
__global__ __launch_bounds__(256, 3) void proj_kernel(
    const half_t* __restrict__ xh, const half_t* __restrict__ wh,
    const float* __restrict__ bq, const float* __restrict__ bk,
    const float* __restrict__ bv, const float* __restrict__ qr,
    const float* __restrict__ qi, const float* __restrict__ kr,
    const float* __restrict__ ki, half_t* __restrict__ Qh,
    half_t* __restrict__ Kh, half_t* __restrict__ Vth) {
  __shared__ __align__(16) char ldsb[32768];
  const int z = blockIdx.z;
  const half_t* Bt = wh + (size_t)z * 1048576;
  const int m0 = blockIdx.x * 128, n0 = blockIdx.y * 128;
  const int tid = threadIdx.x;

  const float* nr = (z == 0) ? qr : kr;
  const float* ni_ = (z == 0) ? qi : ki;
  // noise prefetch (z<2): heads hd0, hd0+1; t-chunk [tt0, tt0+128) -> 8192 f32 each
  if (z < 2) {
    const int hd0 = n0 >> 6;
    const int bb = m0 >> 11, tt0 = m0 & 2047;
    const size_t c0 = ((size_t)(bb * 16 + hd0) * 2048 + tt0) * 64;
    const size_t c1 = ((size_t)(bb * 16 + hd0 + 1) * 2048 + tt0) * 64;
    float t0 = nr[c0 + tid * 32];
    float t1 = nr[c1 + tid * 32];
    float t2 = ni_[c0 + tid * 32];
    float t3 = ni_[c1 + tid * 32];
    asm volatile("" ::"v"(t0), "v"(t1), "v"(t2), "v"(t3));
  }

  f32x4 acc[4][4];
  gemm_core16(xh, Bt, m0, n0, ldsb, acc);

  const int wid = tid >> 6;
  const int lane = tid & 63;
  const int l15 = lane & 15;
  const int l4 = lane >> 4;
  const int wm = wid >> 1, wn = wid & 1;
  const float* bias = (z == 0) ? bq : (z == 1) ? bk : bv;
  const float scale = (z == 0) ? (0.125f * LOG2E) : 1.0f;  // fold 1/8*log2(e) into Q

  if (z == 2) {
    // V transposed: Vt[(b*16+h)*64 + d][t]; regs 0..3 are 4 consecutive t -> hf4 store
#pragma unroll
    for (int mi = 0; mi < 4; mi++) {
      const int tb = m0 + wm * 64 + mi * 16 + l4 * 4;
      const int bb = tb >> 11, tt = tb & 2047;
#pragma unroll
      for (int ni = 0; ni < 4; ni++) {
        const int n = n0 + wn * 64 + ni * 16 + l15;
        const float bsv = bias[n];
        const int hd = n >> 6, d = n & 63;
        hf4 pk;
#pragma unroll
        for (int r = 0; r < 4; r++) pk[r] = (half_t)(acc[mi][ni][r] + bsv);
        *(hf4*)(Vth + (((size_t)(bb * 16 + hd) * 64 + d) * 2048 + tt)) = pk;
      }
    }
  } else {
    half_t* dstp = (z == 0) ? Qh : Kh;
#pragma unroll
    for (int mi = 0; mi < 4; mi++) {
      const int tb = m0 + wm * 64 + mi * 16 + l4 * 4;
      const int bb = tb >> 11, tt = tb & 2047;
#pragma unroll
      for (int ni = 0; ni < 4; ni++) {
        const int n = n0 + wn * 64 + ni * 16 + l15;
        const float bsv = bias[n];
        const int hd = n >> 6, d = n & 63;
        const size_t ibase = ((size_t)(bb * 16 + hd) * 2048 + tt) * 64 + d;
#pragma unroll
        for (int r = 0; r < 4; r++) {
          const size_t idx = ibase + (size_t)r * 64;
          float v = acc[mi][ni][r] + bsv;
          const float a_ = nr[idx], b_ = ni_[idx];
          v += b_ * rsqrtf(a_ * a_ + b_ * b_);  // sin(atan2(b,a)) = b/hypot
          dstp[idx] = (half_t)(v * scale);
        }
      }
    }
  }
}

// ---------------- flash attention v5 (unchanged) ---------------------------------------
template <int CUR>
__device__ __forceinline__ void attn_tile_t(
    bool stage, const half_t* __restrict__ Kb, const half_t* __restrict__ Vb,
    char* base, int qw, int& gk0, int& gk1, int& gv0, int& gv1,
    const int kofs[4], const hf8 qf[4], const f32x16& zv, f32x16 ot[2],
    float& psAcc, hf2 ones) {
  if (stage) {
    gload16(Kb + gk0, base + (CUR ^ 1) * 8192 + qw * 1024);
    gload16(Kb + gk1, base + (CUR ^ 1) * 8192 + 4096 + qw * 1024);
    gload16(Vb + gv0, base + 16384 + (CUR ^ 1) * 8192 + qw * 1024);
    gload16(Vb + gv1, base + 16384 + (CUR ^ 1) * 8192 + 4096 + qw * 1024);
    gk0 += 4096;
    gk1 += 4096;
    gv0 += 64;
    gv1 += 64;
  }
#pragma unroll
  for (int kt = 0; kt < 2; kt++) {
    __builtin_amdgcn_s_setprio(1);
    f32x16 s = __builtin_amdgcn_mfma_f32_32x32x16_f16(
        *(const hf8*)(base + kofs[0] + CUR * 8192 + kt * 4096), qf[0], zv, 0, 0,
        0);
    s = __builtin_amdgcn_mfma_f32_32x32x16_f16(
        *(const hf8*)(base + kofs[1] + CUR * 8192 + kt * 4096), qf[1], s, 0, 0,
        0);
    s = __builtin_amdgcn_mfma_f32_32x32x16_f16(
        *(const hf8*)(base + kofs[2] + CUR * 8192 + kt * 4096), qf[2], s, 0, 0,
        0);
    s = __builtin_amdgcn_mfma_f32_32x32x16_f16(
        *(const hf8*)(base + kofs[3] + CUR * 8192 + kt * 4096), qf[3], s, 0, 0,
        0);
    __builtin_amdgcn_s_setprio(0);

    unsigned pw[8];
#pragma unroll
    for (int j = 0; j < 8; j++) {
      float p0 = exp2fast(s[2 * j]);
      float p1 = exp2fast(s[2 * j + 1]);
      pw[j] = packrtz(p0, p1);
      psAcc = psum2(pw[j], ones, psAcc);
    }

#pragma unroll
    for (int sub = 0; sub < 2; sub++) {
      const int kc = kt * 2 + sub;
      unsigned a0 = pw[sub * 4 + 0], a1 = pw[sub * 4 + 1];
      unsigned a2 = pw[sub * 4 + 2], a3 = pw[sub * 4 + 3];
      union { unsigned u[4]; hf8 v; } pu;
#if __has_builtin(__builtin_amdgcn_permlane32_swap)
      uint2_t r02 = __builtin_amdgcn_permlane32_swap(a0, a2, false, false);
      uint2_t r13 = __builtin_amdgcn_permlane32_swap(a1, a3, false, false);
      pu.u[0] = r02[0];
      pu.u[1] = r13[0];
      pu.u[2] = r02[1];
      pu.u[3] = r13[1];
#else
      const int hh_ = (threadIdx.x & 63) >> 5;
      unsigned x0 = __shfl_xor(a0, 32, 64), x1 = __shfl_xor(a1, 32, 64);
      unsigned x2 = __shfl_xor(a2, 32, 64), x3 = __shfl_xor(a3, 32, 64);
      pu.u[0] = hh_ ? x2 : a0;
      pu.u[1] = hh_ ? x3 : a1;
      pu.u[2] = hh_ ? a2 : x0;
      pu.u[3] = hh_ ? a3 : x1;
#endif
      __builtin_amdgcn_s_setprio(1);
#pragma unroll
      for (int dt = 0; dt < 2; dt++) {
        hf8 vf =
            *(const hf8*)(base + kofs[kc] + 16384 + CUR * 8192 + dt * 4096);
        ot[dt] =
            __builtin_amdgcn_mfma_f32_32x32x16_f16(vf, pu.v, ot[dt], 0, 0, 0);
      }
      __builtin_amdgcn_s_setprio(0);
    }
  }
  __syncthreads();
}

__global__ __launch_bounds__(512, 4) void attn_kernel(
    const half_t* __restrict__ Qh, const half_t* __restrict__ Kh,
    const half_t* __restrict__ Vth, half_t* __restrict__ ah) {
  __shared__ __align__(16) char smem[65536];
  const int tid = threadIdx.x, wid = tid >> 6, lane = tid & 63;
  const int l31 = lane & 31, hh = lane >> 5;
  const int qw = wid & 3, g = wid >> 2;
  const int lin = blockIdx.x;
  const int slot = lin >> 3;
  const int bh = (lin & 7) * 4 + (slot >> 4);  // b*16 + h
  const int qb = slot & 15;
  const int b = bh >> 4, hd = bh & 15;
  const int t = qb * 128 + qw * 32 + l31;

  char* base = smem + g * 32768;

  const half_t* qrow = Qh + ((size_t)bh * 2048 + t) * 64;
  hf8 qf[4];
#pragma unroll
  for (int kc = 0; kc < 4; kc++) qf[kc] = *(const hf8*)(qrow + kc * 16 + hh * 8);

  f32x16 ot[2];
#pragma unroll
  for (int dt = 0; dt < 2; dt++)
#pragma unroll
    for (int i = 0; i < 16; i++) ot[dt][i] = 0.f;
  f32x16 zv;
#pragma unroll
  for (int i = 0; i < 16; i++) zv[i] = 0.f;
  float psAcc = 0.f;
  const hf2 ones = {(_Float16)1.0f, (_Float16)1.0f};

  const half_t* Kb = Kh + (size_t)bh * 2048 * 64;
  const half_t* Vb = Vth + (size_t)bh * 64 * 2048;
  const int kvbase = g * 1024;

  int kofs[4];
#pragma unroll
  for (int kc = 0; kc < 4; kc++)
    kofs[kc] = l31 * 128 + ((kc * 32 + hh * 16) ^ ((l31 & 7) << 4));

  int gk0, gk1, gv0, gv1;
  {
    int c0 = qw * 64 + lane, c1 = 256 + qw * 64 + lane;
    int r0 = c0 >> 3, s0 = (c0 & 7) ^ (r0 & 7);
    int r1 = c1 >> 3, s1 = (c1 & 7) ^ (r1 & 7);
    gk0 = (kvbase + r0) * 64 + s0 * 8;
    gk1 = (kvbase + r1) * 64 + s1 * 8;
    gv0 = r0 * 2048 + kvbase + s0 * 8;
    gv1 = r1 * 2048 + kvbase + s1 * 8;
  }
  gload16(Kb + gk0, base + qw * 1024);
  gload16(Kb + gk1, base + 4096 + qw * 1024);
  gload16(Vb + gv0, base + 16384 + qw * 1024);
  gload16(Vb + gv1, base + 16384 + 4096 + qw * 1024);
  gk0 += 4096;
  gk1 += 4096;
  gv0 += 64;
  gv1 += 64;
  __syncthreads();

  for (int tp = 0; tp < 8; ++tp) {
    attn_tile_t<0>(true, Kb, Vb, base, qw, gk0, gk1, gv0, gv1, kofs, qf, zv,
                   ot, psAcc, ones);
    attn_tile_t<1>(tp < 7, Kb, Vb, base, qw, gk0, gk1, gv0, gv1, kofs, qf, zv,
                   ot, psAcc, ones);
  }

  const float lrun = psAcc + __shfl_xor(psAcc, 32, 64);

  float* cb = (float*)smem;            // [4][2][16][64] f32 = 32KB
  float* lb = (float*)(smem + 32768);  // [4][64]
  if (g == 1) {
#pragma unroll
    for (int dt = 0; dt < 2; dt++)
#pragma unroll
      for (int i = 0; i < 16; i++)
        cb[((qw * 2 + dt) * 16 + i) * 64 + lane] = ot[dt][i];
    lb[qw * 64 + lane] = lrun;
  }
  __syncthreads();
  if (g == 0) {
#pragma unroll
    for (int dt = 0; dt < 2; dt++)
#pragma unroll
      for (int i = 0; i < 16; i++)
        ot[dt][i] += cb[((qw * 2 + dt) * 16 + i) * 64 + lane];
    const float inv = 1.0f / (lrun + lb[qw * 64 + lane]);
    const size_t obase = ((size_t)b * 2048 + t) * 1024 + hd * 64;
#pragma unroll
    for (int dt = 0; dt < 2; dt++)
#pragma unroll
      for (int gg = 0; gg < 4; gg++) {
        hf4 pk;
#pragma unroll
        for (int i2 = 0; i2 < 4; i2++)
          pk[i2] = (half_t)(ot[dt][4 * gg + i2] * inv);
        *(hf4*)(ah + obase + dt * 32 + 8 * gg + 4 * hh) = pk;
      }
  }
}

// ---------------- GEMM core v7b: 128x64 tile (acc[4][2]) for outproj -------------------
// Same algebra as gemm_core16; B-tile 64 rows (8KB). LDS 24KB -> 4+ blocks/CU.
__device__ __forceinline__ void gemm_core16n(const half_t* __restrict__ A,
                                             const half_t* __restrict__ Bt,
                                             int m0, int n0, char* ldsb,
                                             f32x4 acc[4][2]) {
  const int tid = threadIdx.x;
  const int wid = tid >> 6;
  const int lane = tid & 63;
  const int l15 = lane & 15;
  const int l4 = lane >> 4;
  const int wm = wid >> 1, wn = wid & 1;

#pragma unroll
  for (int mi = 0; mi < 4; mi++)
#pragma unroll
    for (int ni = 0; ni < 2; ni++)
#pragma unroll
      for (int i = 0; i < 4; i++) acc[mi][ni][i] = 0.f;

  const int rowb = tid >> 3;
  const int c16 = (tid & 7) ^ (rowb & 7);
  int goA = (m0 + rowb) * 1024 + c16 * 8;
  int goB = (n0 + rowb) * 1024 + c16 * 8;  // rows 0..63 only (i<2)

  const int l7 = lane & 7;
  const int arow = (wm * 64 + l15) * 128;
  const int brow = 16384 + (wn * 32 + l15) * 128;
  const int aks0 = arow + ((l4) ^ l7) * 16;
  const int aks1 = arow + ((4 + l4) ^ l7) * 16;
  const int bks0 = brow + ((l4) ^ l7) * 16;
  const int bks1 = brow + ((4 + l4) ^ l7) * 16;

  for (int kt = 0; kt < 16; ++kt) {
#pragma unroll
    for (int i = 0; i < 4; i++)
      gload16(A + goA + i * 32768, ldsb + i * 4096 + wid * 1024);
#pragma unroll
    for (int i = 0; i < 2; i++)
      gload16(Bt + goB + i * 32768, ldsb + 16384 + i * 4096 + wid * 1024);
    goA += 64;
    goB += 64;
    __syncthreads();
#pragma unroll
    for (int ks = 0; ks < 2; ks++) {
      const int ao = ks ? aks1 : aks0;
      const int bo = ks ? bks1 : bks0;
      hf8 af[4], bf[2];
#pragma unroll
      for (int mi = 0; mi < 4; mi++)
        af[mi] = *(const hf8*)(ldsb + ao + mi * 2048);
#pragma unroll
      for (int ni = 0; ni < 2; ni++)
        bf[ni] = *(const hf8*)(ldsb + bo + ni * 2048);
#pragma unroll
      for (int mi = 0; mi < 4; mi++)
#pragma unroll
        for (int ni = 0; ni < 2; ni++)
          acc[mi][ni] = __builtin_amdgcn_mfma_f32_16x16x32_f16(
              af[mi], bf[ni], acc[mi][ni], 0, 0, 0);
    }
    __syncthreads();
  }
}

// ---------------- output projection: out = attn @ Wo^T + bo (f32 out) ----------------
__global__ __launch_bounds__(256, 4) void outproj_kernel(
    const half_t* __restrict__ ah, const half_t* __restrict__ woh,
    const float* __restrict__ bo, float* __restrict__ out) {
  __shared__ __align__(16) char ldsb[24576];
  const int m0 = blockIdx.x * 128, n0 = blockIdx.y * 64;
  f32x4 acc[4][2];
  gemm_core16n(ah, woh, m0, n0, ldsb, acc);
  const int tid = threadIdx.x, wid = tid >> 6, lane = tid & 63;
  const int l15 = lane & 15, l4 = lane >> 4;
  const int wm = wid >> 1, wn = wid & 1;
#pragma unroll
  for (int mi = 0; mi < 4; mi++) {
    const int mb = m0 + wm * 64 + mi * 16 + l4 * 4;
#pragma unroll
    for (int ni = 0; ni < 2; ni++) {
      const int n = n0 + wn * 32 + ni * 16 + l15;
      const float bsv = bo[n];
#pragma unroll
      for (int r = 0; r < 4; r++)
        out[(size_t)(mb + r) * 1024 + n] = acc[mi][ni][r] + bsv;
    }
  }
}

extern "C" void kernel_launch(void* const* d_in, const int* in_sizes, int n_in,
                              void* d_out, int out_size, void* d_ws,
                              size_t ws_size, hipStream_t stream) {
  const float* x = (const float*)d_in[0];
  const float* Wq = (const float*)d_in[1];
  const float* bq = (const float*)d_in[2];
  const float* Wk = (const float*)d_in[3];
  const float* bk = (const float*)d_in[4];
  const float* Wv = (const float*)d_in[5];
  const float* bv = (const float*)d_in[6];
  const float* Wo = (const float*)d_in[7];
  const float* bo = (const float*)d_in[8];
  const float* qr = (const float*)d_in[9];
  const float* qi = (const float*)d_in[10];
  const float* kr = (const float*)d_in[11];
  const float* ki = (const float*)d_in[12];
  float* out = (float*)d_out;

  char* ws = (char*)d_ws;
  half_t* xh = (half_t*)(ws);                  // 4194304 f16
  half_t* wh = (half_t*)(ws + 8388608);        // 4 x 1048576 f16 (Wq,Wk,Wv,Wo)
  half_t* Qh = (half_t*)(ws + 16777216);       // [B,H,T,64]
  half_t* Kh = (half_t*)(ws + 25165824);       // [B,H,T,64]
  half_t* Vth = (half_t*)(ws + 33554432);      // [B,H,64,T]
  half_t* ah = (half_t*)(ws + 41943040);       // [B,T,D]

  cvt_kernel<<<dim3(2048), dim3(256), 0, stream>>>(x, Wq, Wk, Wv, Wo, xh, wh);
  proj_kernel<<<dim3(32, 8, 3), dim3(256), 0, stream>>>(
      xh, wh, bq, bk, bv, qr, qi, kr, ki, Qh, Kh, Vth);
  attn_kernel<<<dim3(512), dim3(512), 0, stream>>>(Qh, Kh, Vth, ah);
  outproj_kernel<<<dim3(32, 16), dim3(256), 0, stream>>>(ah, wh + 3 * 1048576,
                                                         bo, out);
}

// Round 15
// 116.341 us; speedup vs baseline: 1.0014x; 1.0014x over previous
//
#include <hip/hip_runtime.h>
#include <hip/hip_fp16.h>
#include <stdint.h>

typedef _Float16 half_t;
typedef _Float16 hf2 __attribute__((ext_vector_type(2)));
typedef _Float16 hf4 __attribute__((ext_vector_type(4)));
typedef _Float16 hf8 __attribute__((ext_vector_type(8)));
typedef float f32x4 __attribute__((ext_vector_type(4)));
typedef float f32x16 __attribute__((ext_vector_type(16)));
typedef unsigned uint2_t __attribute__((ext_vector_type(2)));

#define LOG2E 1.4426950408889634f

// async global->LDS, 16B per lane; LDS dest must be wave-uniform base (+lane*16 by HW)
__device__ __forceinline__ void gload16(const void* g, void* l) {
  __builtin_amdgcn_global_load_lds(
      (const __attribute__((address_space(1))) unsigned int*)g,
      (__attribute__((address_space(3))) unsigned int*)l, 16, 0, 0);
}

__device__ __forceinline__ unsigned packrtz(float a, float b) {
  auto h = __builtin_amdgcn_cvt_pkrtz(a, b);
  union { decltype(h) h2; unsigned u; } c;
  c.h2 = h;
  return c.u;
}

__device__ __forceinline__ float exp2fast(float x) {
#if __has_builtin(__builtin_amdgcn_exp2f)
  return __builtin_amdgcn_exp2f(x);
#else
  return exp2f(x);
#endif
}

__device__ __forceinline__ float psum2(unsigned pw, hf2 ones, float acc) {
#if __has_builtin(__builtin_amdgcn_fdot2)
  union { unsigned u; hf2 h; } c;
  c.u = pw;
  return __builtin_amdgcn_fdot2(c.h, ones, acc, false);
#else
  union { unsigned u; hf2 h; } c;
  c.u = pw;
  return acc + (float)c.h[0] + (float)c.h[1];
#endif
}

// ---------------- convert + noise precompute -------------------------------------------
// e < 4.19M: x f32->f16.  < 8.39M: weights.  < 12.58M: nq = qi*rsqrt(qr^2+qi^2) -> f16
// written INTO Qh (proj epilogue reads it, adds GEMM result, overwrites in place —
// same thread/same address, race-free).  < 16.78M: nk -> Kh.  Streaming float4 reads
// replace proj's scattered 256B-stride scalar f32 epilogue reads (67MB -> 16.8MB f16).
__global__ __launch_bounds__(256) void cvt_kernel(
    const float* __restrict__ x, const float* __restrict__ wq,
    const float* __restrict__ wk, const float* __restrict__ wv,
    const float* __restrict__ wo, const float* __restrict__ qr,
    const float* __restrict__ qi, const float* __restrict__ kr,
    const float* __restrict__ ki, half_t* __restrict__ xh,
    half_t* __restrict__ wh, half_t* __restrict__ nqh,
    half_t* __restrict__ nkh) {
  long e = ((long)blockIdx.x * 256 + threadIdx.x) * 16;
  if (e < 8388608L) {
    const float* src;
    half_t* dst;
    if (e < 4194304L) {
      src = x + e;
      dst = xh + e;
    } else {
      long j = e - 4194304L;
      int w = (int)(j >> 20);
      long off = j & 1048575L;
      src = (w == 0 ? wq : w == 1 ? wk : w == 2 ? wv : wo) + off;
      dst = wh + ((long)w << 20) + off;
    }
    const float4* s4 = (const float4*)src;
    float4 f0 = s4[0], f1 = s4[1], f2 = s4[2], f3 = s4[3];
    hf8 o0 = {(half_t)f0.x, (half_t)f0.y, (half_t)f0.z, (half_t)f0.w,
              (half_t)f1.x, (half_t)f1.y, (half_t)f1.z, (half_t)f1.w};
    hf8 o1 = {(half_t)f2.x, (half_t)f2.y, (half_t)f2.z, (half_t)f2.w,
              (half_t)f3.x, (half_t)f3.y, (half_t)f3.z, (half_t)f3.w};
    *(hf8*)dst = o0;
    *(hf8*)(dst + 8) = o1;
  } else {
    long o;
    const float* re;
    const float* im;
    half_t* dst;
    if (e < 12582912L) {
      o = e - 8388608L;
      re = qr;
      im = qi;
      dst = nqh;
    } else {
      o = e - 12582912L;
      re = kr;
      im = ki;
      dst = nkh;
    }
    const float4* r4 = (const float4*)(re + o);
    const float4* i4 = (const float4*)(im + o);
    hf8 o0, o1;
#pragma unroll
    for (int c = 0; c < 2; c++) {
      float4 ra = r4[2 * c], rb = r4[2 * c + 1];
      float4 ia = i4[2 * c], ib = i4[2 * c + 1];
      hf8 ov;
      ov[0] = (half_t)(ia.x * rsqrtf(ra.x * ra.x + ia.x * ia.x));
      ov[1] = (half_t)(ia.y * rsqrtf(ra.y * ra.y + ia.y * ia.y));
      ov[2] = (half_t)(ia.z * rsqrtf(ra.z * ra.z + ia.z * ia.z));
      ov[3] = (half_t)(ia.w * rsqrtf(ra.w * ra.w + ia.w * ia.w));
      ov[4] = (half_t)(ib.x * rsqrtf(rb.x * rb.x + ib.x * ib.x));
      ov[5] = (half_t)(ib.y * rsqrtf(rb.y * rb.y + ib.y * ib.y));
      ov[6] = (half_t)(ib.z * rsqrtf(rb.z * rb.z + ib.z * ib.z));
      ov[7] = (half_t)(ib.w * rsqrtf(rb.w * rb.w + ib.w * ib.w));
      if (c == 0)
        o0 = ov;
      else
        o1 = ov;
    }
    *(hf8*)(dst + o) = o0;
    *(hf8*)(dst + o + 8) = o1;
  }
}

// ---------------- GEMM core v7 (r13): 128x128, BK=64, 16x16x32, acc[4][4] -------------
// LDS 32KB: A[128][64]f16 at [0,16K), Bt[128][64] at [16K,32K). Row r at byte r*128
// (8 16B slots); slot s stored at s^(r&7); staging source pre-swizzled inverse.
// Fragment layouts (m89/m91): A/B operand row(col)=lane&15, k=(lane>>4)*8+j (16B);
// C/D: col=lane&15, row=(lane>>4)*4+reg. Bank-conflict-free (r13 PMC: 0).
__device__ __forceinline__ void gemm_core16(const half_t* __restrict__ A,
                                            const half_t* __restrict__ Bt,
                                            int m0, int n0, char* ldsb,
                                            f32x4 acc[4][4]) {
  const int tid = threadIdx.x;
  const int wid = tid >> 6;
  const int lane = tid & 63;
  const int l15 = lane & 15;
  const int l4 = lane >> 4;
  const int wm = wid >> 1, wn = wid & 1;

#pragma unroll
  for (int mi = 0; mi < 4; mi++)
#pragma unroll
    for (int ni = 0; ni < 4; ni++)
#pragma unroll
      for (int i = 0; i < 4; i++) acc[mi][ni][i] = 0.f;

  const int rowb = tid >> 3;
  const int c16 = (tid & 7) ^ (rowb & 7);
  int goA = (m0 + rowb) * 1024 + c16 * 8;
  int goB = (n0 + rowb) * 1024 + c16 * 8;

  const int l7 = lane & 7;
  const int arow = (wm * 64 + l15) * 128;
  const int brow = 16384 + (wn * 64 + l15) * 128;
  const int aks0 = arow + ((l4) ^ l7) * 16;
  const int aks1 = arow + ((4 + l4) ^ l7) * 16;
  const int bks0 = brow + ((l4) ^ l7) * 16;
  const int bks1 = brow + ((4 + l4) ^ l7) * 16;

  for (int kt = 0; kt < 16; ++kt) {
#pragma unroll
    for (int i = 0; i < 4; i++) {
      gload16(A + goA + i * 32768, ldsb + i * 4096 + wid * 1024);
      gload16(Bt + goB + i * 32768, ldsb + 16384 + i * 4096 + wid * 1024);
    }
    goA += 64;
    goB += 64;
    __syncthreads();
#pragma unroll
    for (int ks = 0; ks < 2; ks++) {
      const int ao = ks ? aks1 : aks0;
      const int bo = ks ? bks1 : bks0;
      hf8 af[4], bf[4];
#pragma unroll
      for (int mi = 0; mi < 4; mi++)
        af[mi] = *(const hf8*)(ldsb + ao + mi * 2048);
#pragma unroll
      for (int ni = 0; ni < 4; ni++)
        bf[ni] = *(const hf8*)(ldsb + bo + ni * 2048);
#pragma unroll
      for (int mi = 0; mi < 4; mi++)
#pragma unroll
        for (int ni = 0; ni < 4; ni++)
          acc[mi][ni] = __builtin_amdgcn_mfma_f32_16x16x32_f16(
              af[mi], bf[ni], acc[mi][ni], 0, 0, 0);
    }
    __syncthreads();
  }
}

// ---------------- QKV projection (z=0:Q, 1:K, 2:V) ------------------------------------
// Q/K epilogue: dstp[idx] holds the PRE-COMPUTED f16 noise (written by cvt); read it,
// add GEMM+bias, overwrite in place (same thread/address — race-free).
__global__ __launch_bounds__(256, 3) void proj_kernel(
    const half_t* __restrict__ xh, const half_t* __restrict__ wh,
    const float* __restrict__ bq, const float* __restrict__ bk,
    const float* __restrict__ bv, half_t* __restrict__ Qh,
    half_t* __restrict__ Kh, half_t* __restrict__ Vth) {
  __shared__ __align__(16) char ldsb[32768];
  const int z = blockIdx.z;
  const half_t* Bt = wh + (size_t)z * 1048576;
  const int m0 = blockIdx.x * 128, n0 = blockIdx.y * 128;
  f32x4 acc[4][4];
  gemm_core16(xh, Bt, m0, n0, ldsb, acc);

  const int tid = threadIdx.x;
  const int wid = tid >> 6;
  const int lane = tid & 63;
  const int l15 = lane & 15;
  const int l4 = lane >> 4;
  const int wm = wid >> 1, wn = wid & 1;
  const float* bias = (z == 0) ? bq : (z == 1) ? bk : bv;
  const float scale = (z == 0) ? (0.125f * LOG2E) : 1.0f;  // fold 1/8*log2(e) into Q

  if (z == 2) {
    // V transposed: Vt[(b*16+h)*64 + d][t]; regs 0..3 are 4 consecutive t -> hf4 store
#pragma unroll
    for (int mi = 0; mi < 4; mi++) {
      const int tb = m0 + wm * 64 + mi * 16 + l4 * 4;
      const int bb = tb >> 11, tt = tb & 2047;
#pragma unroll
      for (int ni = 0; ni < 4; ni++) {
        const int n = n0 + wn * 64 + ni * 16 + l15;
        const float bsv = bias[n];
        const int hd = n >> 6, d = n & 63;
        hf4 pk;
#pragma unroll
        for (int r = 0; r < 4; r++) pk[r] = (half_t)(acc[mi][ni][r] + bsv);
        *(hf4*)(Vth + (((size_t)(bb * 16 + hd) * 64 + d) * 2048 + tt)) = pk;
      }
    }
  } else {
    half_t* dstp = (z == 0) ? Qh : Kh;
#pragma unroll
    for (int mi = 0; mi < 4; mi++) {
      const int tb = m0 + wm * 64 + mi * 16 + l4 * 4;
      const int bb = tb >> 11, tt = tb & 2047;
#pragma unroll
      for (int ni = 0; ni < 4; ni++) {
        const int n = n0 + wn * 64 + ni * 16 + l15;
        const float bsv = bias[n];
        const int hd = n >> 6, d = n & 63;
        const size_t ibase = ((size_t)(bb * 16 + hd) * 2048 + tt) * 64 + d;
#pragma unroll
        for (int r = 0; r < 4; r++) {
          const size_t idx = ibase + (size_t)r * 64;
          const float v = acc[mi][ni][r] + bsv + (float)dstp[idx];
          dstp[idx] = (half_t)(v * scale);
        }
      }
    }
  }
}

// ---------------- flash attention v5 (unchanged) ---------------------------------------
template <int CUR>
__device__ __forceinline__ void attn_tile_t(
    bool stage, const half_t* __restrict__ Kb, const half_t* __restrict__ Vb,
    char* base, int qw, int& gk0, int& gk1, int& gv0, int& gv1,
    const int kofs[4], const hf8 qf[4], const f32x16& zv, f32x16 ot[2],
    float& psAcc, hf2 ones) {
  if (stage) {
    gload16(Kb + gk0, base + (CUR ^ 1) * 8192 + qw * 1024);
    gload16(Kb + gk1, base + (CUR ^ 1) * 8192 + 4096 + qw * 1024);
    gload16(Vb + gv0, base + 16384 + (CUR ^ 1) * 8192 + qw * 1024);
    gload16(Vb + gv1, base + 16384 + (CUR ^ 1) * 8192 + 4096 + qw * 1024);
    gk0 += 4096;
    gk1 += 4096;
    gv0 += 64;
    gv1 += 64;
  }
#pragma unroll
  for (int kt = 0; kt < 2; kt++) {
    __builtin_amdgcn_s_setprio(1);
    f32x16 s = __builtin_amdgcn_mfma_f32_32x32x16_f16(
        *(const hf8*)(base + kofs[0] + CUR * 8192 + kt * 4096), qf[0], zv, 0, 0,
        0);
    s = __builtin_amdgcn_mfma_f32_32x32x16_f16(
        *(const hf8*)(base + kofs[1] + CUR * 8192 + kt * 4096), qf[1], s, 0, 0,
        0);
    s = __builtin_amdgcn_mfma_f32_32x32x16_f16(
        *(const hf8*)(base + kofs[2] + CUR * 8192 + kt * 4096), qf[2], s, 0, 0,
        0);
    s = __builtin_amdgcn_mfma_f32_32x32x16_f16(
        *(const hf8*)(base + kofs[3] + CUR * 8192 + kt * 4096), qf[3], s, 0, 0,
        0);
    __builtin_amdgcn_s_setprio(0);

    unsigned pw[8];
#pragma unroll
    for (int j = 0; j < 8; j++) {
      float p0 = exp2fast(s[2 * j]);
      float p1 = exp2fast(s[2 * j + 1]);
      pw[j] = packrtz(p0, p1);
      psAcc = psum2(pw[j], ones, psAcc);
    }

#pragma unroll
    for (int sub = 0; sub < 2; sub++) {
      const int kc = kt * 2 + sub;
      unsigned a0 = pw[sub * 4 + 0], a1 = pw[sub * 4 + 1];
      unsigned a2 = pw[sub * 4 + 2], a3 = pw[sub * 4 + 3];
      union { unsigned u[4]; hf8 v; } pu;
#if __has_builtin(__builtin_amdgcn_permlane32_swap)
      uint2_t r02 = __builtin_amdgcn_permlane32_swap(a0, a2, false, false);
      uint2_t r13 = __builtin_amdgcn_permlane32_swap(a1, a3, false, false);
      pu.u[0] = r02[0];
      pu.u[1] = r13[0];
      pu.u[2] = r02[1];
      pu.u[3] = r13[1];
#else
      const int hh_ = (threadIdx.x & 63) >> 5;
      unsigned x0 = __shfl_xor(a0, 32, 64), x1 = __shfl_xor(a1, 32, 64);
      unsigned x2 = __shfl_xor(a2, 32, 64), x3 = __shfl_xor(a3, 32, 64);
      pu.u[0] = hh_ ? x2 : a0;
      pu.u[1] = hh_ ? x3 : a1;
      pu.u[2] = hh_ ? a2 : x0;
      pu.u[3] = hh_ ? a3 : x1;
#endif
      __builtin_amdgcn_s_setprio(1);
#pragma unroll
      for (int dt = 0; dt < 2; dt++) {
        hf8 vf =
            *(const hf8*)(base + kofs[kc] + 16384 + CUR * 8192 + dt * 4096);
        ot[dt] =
            __builtin_amdgcn_mfma_f32_32x32x16_f16(vf, pu.v, ot[dt], 0, 0, 0);
      }
      __builtin_amdgcn_s_setprio(0);
    }
  }
  __syncthreads();
}

__global__ __launch_bounds__(512, 4) void attn_kernel(
    const half_t* __restrict__ Qh, const half_t* __restrict__ Kh,
    const half_t* __restrict__ Vth, half_t* __restrict__ ah) {
  __shared__ __align__(16) char smem[65536];
  const int tid = threadIdx.x, wid = tid >> 6, lane = tid & 63;
  const int l31 = lane & 31, hh = lane >> 5;
  const int qw = wid & 3, g = wid >> 2;
  const int lin = blockIdx.x;
  const int slot = lin >> 3;
  const int bh = (lin & 7) * 4 + (slot >> 4);  // b*16 + h
  const int qb = slot & 15;
  const int b = bh >> 4, hd = bh & 15;
  const int t = qb * 128 + qw * 32 + l31;

  char* base = smem + g * 32768;

  const half_t* qrow = Qh + ((size_t)bh * 2048 + t) * 64;
  hf8 qf[4];
#pragma unroll
  for (int kc = 0; kc < 4; kc++) qf[kc] = *(const hf8*)(qrow + kc * 16 + hh * 8);

  f32x16 ot[2];
#pragma unroll
  for (int dt = 0; dt < 2; dt++)
#pragma unroll
    for (int i = 0; i < 16; i++) ot[dt][i] = 0.f;
  f32x16 zv;
#pragma unroll
  for (int i = 0; i < 16; i++) zv[i] = 0.f;
  float psAcc = 0.f;
  const hf2 ones = {(_Float16)1.0f, (_Float16)1.0f};

  const half_t* Kb = Kh + (size_t)bh * 2048 * 64;
  const half_t* Vb = Vth + (size_t)bh * 64 * 2048;
  const int kvbase = g * 1024;

  int kofs[4];
#pragma unroll
  for (int kc = 0; kc < 4; kc++)
    kofs[kc] = l31 * 128 + ((kc * 32 + hh * 16) ^ ((l31 & 7) << 4));

  int gk0, gk1, gv0, gv1;
  {
    int c0 = qw * 64 + lane, c1 = 256 + qw * 64 + lane;
    int r0 = c0 >> 3, s0 = (c0 & 7) ^ (r0 & 7);
    int r1 = c1 >> 3, s1 = (c1 & 7) ^ (r1 & 7);
    gk0 = (kvbase + r0) * 64 + s0 * 8;
    gk1 = (kvbase + r1) * 64 + s1 * 8;
    gv0 = r0 * 2048 + kvbase + s0 * 8;
    gv1 = r1 * 2048 + kvbase + s1 * 8;
  }
  gload16(Kb + gk0, base + qw * 1024);
  gload16(Kb + gk1, base + 4096 + qw * 1024);
  gload16(Vb + gv0, base + 16384 + qw * 1024);
  gload16(Vb + gv1, base + 16384 + 4096 + qw * 1024);
  gk0 += 4096;
  gk1 += 4096;
  gv0 += 64;
  gv1 += 64;
  __syncthreads();

  for (int tp = 0; tp < 8; ++tp) {
    attn_tile_t<0>(true, Kb, Vb, base, qw, gk0, gk1, gv0, gv1, kofs, qf, zv,
                   ot, psAcc, ones);
    attn_tile_t<1>(tp < 7, Kb, Vb, base, qw, gk0, gk1, gv0, gv1, kofs, qf, zv,
                   ot, psAcc, ones);
  }

  const float lrun = psAcc + __shfl_xor(psAcc, 32, 64);

  float* cb = (float*)smem;            // [4][2][16][64] f32 = 32KB
  float* lb = (float*)(smem + 32768);  // [4][64]
  if (g == 1) {
#pragma unroll
    for (int dt = 0; dt < 2; dt++)
#pragma unroll
      for (int i = 0; i < 16; i++)
        cb[((qw * 2 + dt) * 16 + i) * 64 + lane] = ot[dt][i];
    lb[qw * 64 + lane] = lrun;
  }
  __syncthreads();
  if (g == 0) {
#pragma unroll
    for (int dt = 0; dt < 2; dt++)
#pragma unroll
      for (int i = 0; i < 16; i++)
        ot[dt][i] += cb[((qw * 2 + dt) * 16 + i) * 64 + lane];
    const float inv = 1.0f / (lrun + lb[qw * 64 + lane]);
    const size_t obase = ((size_t)b * 2048 + t) * 1024 + hd * 64;
#pragma unroll
    for (int dt = 0; dt < 2; dt++)
#pragma unroll
      for (int gg = 0; gg < 4; gg++) {
        hf4 pk;
#pragma unroll
        for (int i2 = 0; i2 < 4; i2++)
          pk[i2] = (half_t)(ot[dt][4 * gg + i2] * inv);
        *(hf4*)(ah + obase + dt * 32 + 8 * gg + 4 * hh) = pk;
      }
  }
}

// ---------------- output projection: out = attn @ Wo^T + bo (f32 out) ----------------
__global__ __launch_bounds__(256, 3) void outproj_kernel(
    const half_t* __restrict__ ah, const half_t* __restrict__ woh,
    const float* __restrict__ bo, float* __restrict__ out) {
  __shared__ __align__(16) char ldsb[32768];
  const int m0 = blockIdx.x * 128, n0 = blockIdx.y * 128;
  f32x4 acc[4][4];
  gemm_core16(ah, woh, m0, n0, ldsb, acc);
  const int tid = threadIdx.x, wid = tid >> 6, lane = tid & 63;
  const int l15 = lane & 15, l4 = lane >> 4;
  const int wm = wid >> 1, wn = wid & 1;
#pragma unroll
  for (int mi = 0; mi < 4; mi++) {
    const int mb = m0 + wm * 64 + mi * 16 + l4 * 4;
#pragma unroll
    for (int ni = 0; ni < 4; ni++) {
      const int n = n0 + wn * 64 + ni * 16 + l15;
      const float bsv = bo[n];
#pragma unroll
      for (int r = 0; r < 4; r++)
        out[(size_t)(mb + r) * 1024 + n] = acc[mi][ni][r] + bsv;
    }
  }
}

extern "C" void kernel_launch(void* const* d_in, const int* in_sizes, int n_in,
                              void* d_out, int out_size, void* d_ws,
                              size_t ws_size, hipStream_t stream) {
  const float* x = (const float*)d_in[0];
  const float* Wq = (const float*)d_in[1];
  const float* bq = (const float*)d_in[2];
  const float* Wk = (const float*)d_in[3];
  const float* bk = (const float*)d_in[4];
  const float* Wv = (const float*)d_in[5];
  const float* bv = (const float*)d_in[6];
  const float* Wo = (const float*)d_in[7];
  const float* bo = (const float*)d_in[8];
  const float* qr = (const float*)d_in[9];
  const float* qi = (const float*)d_in[10];
  const float* kr = (const float*)d_in[11];
  const float* ki = (const float*)d_in[12];
  float* out = (float*)d_out;

  char* ws = (char*)d_ws;
  half_t* xh = (half_t*)(ws);                  // 4194304 f16
  half_t* wh = (half_t*)(ws + 8388608);        // 4 x 1048576 f16 (Wq,Wk,Wv,Wo)
  half_t* Qh = (half_t*)(ws + 16777216);       // [B,H,T,64] (cvt pre-fills noise)
  half_t* Kh = (half_t*)(ws + 25165824);       // [B,H,T,64] (cvt pre-fills noise)
  half_t* Vth = (half_t*)(ws + 33554432);      // [B,H,64,T]
  half_t* ah = (half_t*)(ws + 41943040);       // [B,T,D]

  cvt_kernel<<<dim3(4096), dim3(256), 0, stream>>>(x, Wq, Wk, Wv, Wo, qr, qi,
                                                   kr, ki, xh, wh, Qh, Kh);
  proj_kernel<<<dim3(32, 8, 3), dim3(256), 0, stream>>>(xh, wh, bq, bk, bv, Qh,
                                                        Kh, Vth);
  attn_kernel<<<dim3(512), dim3(512), 0, stream>>>(Qh, Kh, Vth, ah);
  outproj_kernel<<<dim3(32, 8), dim3(256), 0, stream>>>(ah, wh + 3 * 1048576,
                                                        bo, out);
}

// Round 16
// 108.262 us; speedup vs baseline: 1.0761x; 1.0746x over previous
//
#include <hip/hip_runtime.h>
#include <hip/hip_fp16.h>
#include <stdint.h>

typedef _Float16 half_t;
typedef _Float16 hf2 __attribute__((ext_vector_type(2)));
typedef _Float16 hf4 __attribute__((ext_vector_type(4)));
typedef _Float16 hf8 __attribute__((ext_vector_type(8)));
typedef float f32x16 __attribute__((ext_vector_type(16)));
typedef unsigned uint2_t __attribute__((ext_vector_type(2)));

#define LOG2E 1.4426950408889634f

// async global->LDS, 16B per lane; LDS dest must be wave-uniform base (+lane*16 by HW)
__device__ __forceinline__ void gload16(const void* g, void* l) {
  __builtin_amdgcn_global_load_lds(
      (const __attribute__((address_space(1))) unsigned int*)g,
      (__attribute__((address_space(3))) unsigned int*)l, 16, 0, 0);
}

__device__ __forceinline__ unsigned packrtz(float a, float b) {
  auto h = __builtin_amdgcn_cvt_pkrtz(a, b);
  union { decltype(h) h2; unsigned u; } c;
  c.h2 = h;
  return c.u;
}

__device__ __forceinline__ float exp2fast(float x) {
#if __has_builtin(__builtin_amdgcn_exp2f)
  return __builtin_amdgcn_exp2f(x);
#else
  return exp2f(x);
#endif
}

__device__ __forceinline__ float psum2(unsigned pw, hf2 ones, float acc) {
#if __has_builtin(__builtin_amdgcn_fdot2)
  union { unsigned u; hf2 h; } c;
  c.u = pw;
  return __builtin_amdgcn_fdot2(c.h, ones, acc, false);
#else
  union { unsigned u; hf2 h; } c;
  c.u = pw;
  return acc + (float)c.h[0] + (float)c.h[1];
#endif
}

// ---------------- convert f32 -> f16 (x: 4194304 elems, then 4 weights of 1048576) ----
__global__ __launch_bounds__(256) void cvt_kernel(
    const float* __restrict__ x, const float* __restrict__ wq,
    const float* __restrict__ wk, const float* __restrict__ wv,
    const float* __restrict__ wo, half_t* __restrict__ xh,
    half_t* __restrict__ wh) {
  long e = ((long)blockIdx.x * 256 + threadIdx.x) * 16;
  const float* src;
  half_t* dst;
  if (e < 4194304L) {
    src = x + e;
    dst = xh + e;
  } else {
    long j = e - 4194304L;
    int w = (int)(j >> 20);
    long off = j & 1048575L;
    src = (w == 0 ? wq : w == 1 ? wk : w == 2 ? wv : wo) + off;
    dst = wh + ((long)w << 20) + off;
  }
  const float4* s4 = (const float4*)src;
  float4 f0 = s4[0], f1 = s4[1], f2 = s4[2], f3 = s4[3];
  hf8 o0 = {(half_t)f0.x, (half_t)f0.y, (half_t)f0.z, (half_t)f0.w,
            (half_t)f1.x, (half_t)f1.y, (half_t)f1.z, (half_t)f1.w};
  hf8 o1 = {(half_t)f2.x, (half_t)f2.y, (half_t)f2.z, (half_t)f2.w,
            (half_t)f3.x, (half_t)f3.y, (half_t)f3.z, (half_t)f3.w};
  *(hf8*)dst = o0;
  *(hf8*)(dst + 8) = o1;
}

// ---------------- GEMM core v6 (r10): 128x64 tile, double-buffered ---------------------
// A: [M x 1024] row-major f16.  Bt: [N x 1024] row-major f16 (i.e. B transposed).
// LDS 48KB: A bufs [0,16K),[16K,32K); B bufs [32K,40K),[40K,48K).
// Row r at byte r*128 in-tile; slot ^= (r&7)<<4; staging source pre-swizzled with the
// same involution. Step t: stage tile t+1 into buf CUR^1, compute buf CUR, one
// __syncthreads (compiler-managed waits — proven-safe; counted-vmcnt parked per r7/r8).
template <int CUR>
__device__ __forceinline__ void gstep(bool stage, const half_t* __restrict__ A,
                                      const half_t* __restrict__ Bt, char* ldsb,
                                      int wid, int& goA, int& goB, int aof0,
                                      int aof1, int aof2, int aof3, int bof0,
                                      int bof1, int bof2, int bof3,
                                      f32x16 acc[2]) {
  if (stage) {
#pragma unroll
    for (int i = 0; i < 4; i++)
      gload16(A + goA + i * 32768,
              ldsb + (CUR ^ 1) * 16384 + i * 4096 + wid * 1024);
#pragma unroll
    for (int i = 0; i < 2; i++)
      gload16(Bt + goB + i * 32768,
              ldsb + 32768 + (CUR ^ 1) * 8192 + i * 4096 + wid * 1024);
    goA += 64;
    goB += 64;
  }
  constexpr int ca = CUR * 16384;
  constexpr int cb = 32768 + CUR * 8192;
#pragma unroll
  for (int kc = 0; kc < 4; kc++) {
    const int ao = (kc == 0 ? aof0 : kc == 1 ? aof1 : kc == 2 ? aof2 : aof3);
    const int bo = (kc == 0 ? bof0 : kc == 1 ? bof1 : kc == 2 ? bof2 : bof3);
    hf8 af0 = *(const hf8*)(ldsb + ca + ao);
    hf8 af1 = *(const hf8*)(ldsb + ca + ao + 4096);
    hf8 bf = *(const hf8*)(ldsb + cb + bo);
    acc[0] = __builtin_amdgcn_mfma_f32_32x32x16_f16(af0, bf, acc[0], 0, 0, 0);
    acc[1] = __builtin_amdgcn_mfma_f32_32x32x16_f16(af1, bf, acc[1], 0, 0, 0);
  }
  __syncthreads();
}

__device__ __forceinline__ void gemm_core(const half_t* __restrict__ A,
                                          const half_t* __restrict__ Bt,
                                          int m0, int n0, char* ldsb,
                                          f32x16 acc[2]) {
  const int tid = threadIdx.x;
  const int wid = tid >> 6;
  const int lane = tid & 63;
  const int l31 = lane & 31;
  const int hh = lane >> 5;
  const int wm = wid >> 1, wn = wid & 1;

#pragma unroll
  for (int mt = 0; mt < 2; mt++)
#pragma unroll
    for (int i = 0; i < 16; i++) acc[mt][i] = 0.f;

  // staging: chunk c = i*256 + tid; row = i*32 + (tid>>3); slot s' = tid&7;
  // source pre-swizzled: c16 = (tid&7) ^ (row&7)  (row&7 == (tid>>3)&7, i*32 ≡ 0 mod 8)
  const int rowb = tid >> 3;
  const int c16 = (tid & 7) ^ (rowb & 7);
  int goA = (m0 + rowb) * 1024 + c16 * 8;  // + i*32768 (32 rows), advances +64/kt
  int goB = (n0 + rowb) * 1024 + c16 * 8;  // + i*32768, i<2

  // hoisted LDS read byte offsets (within a tile buffer); mt is a +4096 immediate
  const int swz0 = (hh * 16) ^ ((l31 & 7) << 4);
  const int swz1 = (32 + hh * 16) ^ ((l31 & 7) << 4);
  const int swz2 = (64 + hh * 16) ^ ((l31 & 7) << 4);
  const int swz3 = (96 + hh * 16) ^ ((l31 & 7) << 4);
  const int arow = (wm * 64 + l31) * 128;
  const int brow = (wn * 32 + l31) * 128;
  const int aof0 = arow + swz0, aof1 = arow + swz1, aof2 = arow + swz2,
            aof3 = arow + swz3;
  const int bof0 = brow + swz0, bof1 = brow + swz1, bof2 = brow + swz2,
            bof3 = brow + swz3;

  // prologue: stage tile 0 into buf 0
#pragma unroll
  for (int i = 0; i < 4; i++)
    gload16(A + goA + i * 32768, ldsb + i * 4096 + wid * 1024);
#pragma unroll
  for (int i = 0; i < 2; i++)
    gload16(Bt + goB + i * 32768, ldsb + 32768 + i * 4096 + wid * 1024);
  goA += 64;
  goB += 64;
  __syncthreads();

  for (int kp = 0; kp < 8; ++kp) {
    gstep<0>(true, A, Bt, ldsb, wid, goA, goB, aof0, aof1, aof2, aof3, bof0,
             bof1, bof2, bof3, acc);
    gstep<1>(kp < 7, A, Bt, ldsb, wid, goA, goB, aof0, aof1, aof2, aof3, bof0,
             bof1, bof2, bof3, acc);
  }
}

// ---------------- QKV projection (z=0:Q, 1:K, 2:V) ------------------------------------
// C/D layout: col = lane&31 (=n-local), row = (reg&3)+8*(reg>>2)+4*(lane>>5) (=m-local)
__global__ __launch_bounds__(256, 3) void proj_kernel(
    const half_t* __restrict__ xh, const half_t* __restrict__ wh,
    const float* __restrict__ bq, const float* __restrict__ bk,
    const float* __restrict__ bv, const float* __restrict__ qr,
    const float* __restrict__ qi, const float* __restrict__ kr,
    const float* __restrict__ ki, half_t* __restrict__ Qh,
    half_t* __restrict__ Kh, half_t* __restrict__ Vth) {
  __shared__ __align__(16) char ldsb[49152];
  const int z = blockIdx.z;
  const half_t* Bt = wh + (size_t)z * 1048576;
  const int m0 = blockIdx.x * 128, n0 = blockIdx.y * 64;
  f32x16 acc[2];
  gemm_core(xh, Bt, m0, n0, ldsb, acc);

  const int tid = threadIdx.x;
  const int wid = tid >> 6;
  const int lane = tid & 63;
  const int l31 = lane & 31;
  const int hh = lane >> 5;
  const int wm = wid >> 1, wn = wid & 1;
  const float* bias = (z == 0) ? bq : (z == 1) ? bk : bv;
  const float* nr = (z == 0) ? qr : kr;
  const float* ni = (z == 0) ? qi : ki;
  const float scale = (z == 0) ? (0.125f * LOG2E) : 1.0f;  // fold 1/sqrt(64)*log2(e) into Q

  const int n = n0 + wn * 32 + l31;
  const float bsv = bias[n];
  const int hd = n >> 6, d = n & 63;
#pragma unroll
  for (int mt = 0; mt < 2; mt++) {
    const int mbase = m0 + wm * 64 + mt * 32;
    if (z == 2) {
      // V stored transposed: Vt[(b*16+h)*64 + d][t], 4 consecutive t per 8B store
#pragma unroll
      for (int g = 0; g < 4; g++) {
        const int m = mbase + 8 * g + 4 * hh;
        const int bb = m >> 11, tt = m & 2047;
        hf4 pk;
#pragma unroll
        for (int i2 = 0; i2 < 4; i2++)
          pk[i2] = (half_t)(acc[mt][4 * g + i2] + bsv);
        *(hf4*)(Vth + (((size_t)(bb * 16 + hd) * 64 + d) * 2048 + tt)) = pk;
      }
    } else {
      half_t* dstp = (z == 0) ? Qh : Kh;
#pragma unroll
      for (int r = 0; r < 16; r++) {
        const int m = mbase + (r & 3) + 8 * (r >> 2) + 4 * hh;
        const int bb = m >> 11, tt = m & 2047;
        const size_t idx = ((size_t)(bb * 16 + hd) * 2048 + tt) * 64 + d;
        float v = acc[mt][r] + bsv;
        const float a_ = nr[idx], b_ = ni[idx];
        v += b_ * rsqrtf(a_ * a_ + b_ * b_);  // sin(atan2(b,a)) = b/hypot
        dstp[idx] = (half_t)(v * scale);
      }
    }
  }
}

// ---------------- flash attention v5 (r10, unchanged) ----------------------------------
template <int CUR>
__device__ __forceinline__ void attn_tile_t(
    bool stage, const half_t* __restrict__ Kb, const half_t* __restrict__ Vb,
    char* base, int qw, int& gk0, int& gk1, int& gv0, int& gv1,
    const int kofs[4], const hf8 qf[4], const f32x16& zv, f32x16 ot[2],
    float& psAcc, hf2 ones) {
  if (stage) {
    gload16(Kb + gk0, base + (CUR ^ 1) * 8192 + qw * 1024);
    gload16(Kb + gk1, base + (CUR ^ 1) * 8192 + 4096 + qw * 1024);
    gload16(Vb + gv0, base + 16384 + (CUR ^ 1) * 8192 + qw * 1024);
    gload16(Vb + gv1, base + 16384 + (CUR ^ 1) * 8192 + 4096 + qw * 1024);
    gk0 += 4096;
    gk1 += 4096;
    gv0 += 64;
    gv1 += 64;
  }
#pragma unroll
  for (int kt = 0; kt < 2; kt++) {
    // S^T[key, q] for 32 keys: lane holds col q=l31, key rows (r&3)+8*(r>>2)+4*hh
    __builtin_amdgcn_s_setprio(1);
    f32x16 s = __builtin_amdgcn_mfma_f32_32x32x16_f16(
        *(const hf8*)(base + kofs[0] + CUR * 8192 + kt * 4096), qf[0], zv, 0, 0,
        0);
    s = __builtin_amdgcn_mfma_f32_32x32x16_f16(
        *(const hf8*)(base + kofs[1] + CUR * 8192 + kt * 4096), qf[1], s, 0, 0,
        0);
    s = __builtin_amdgcn_mfma_f32_32x32x16_f16(
        *(const hf8*)(base + kofs[2] + CUR * 8192 + kt * 4096), qf[2], s, 0, 0,
        0);
    s = __builtin_amdgcn_mfma_f32_32x32x16_f16(
        *(const hf8*)(base + kofs[3] + CUR * 8192 + kt * 4096), qf[3], s, 0, 0,
        0);
    __builtin_amdgcn_s_setprio(0);

    // M=0 softmax: p = 2^s (scale cancels between O and l); pack + dot2-psum
    unsigned pw[8];
#pragma unroll
    for (int j = 0; j < 8; j++) {
      float p0 = exp2fast(s[2 * j]);
      float p1 = exp2fast(s[2 * j + 1]);
      pw[j] = packrtz(p0, p1);
      psAcc = psum2(pw[j], ones, psAcc);
    }

    // P -> f16 B-operand frags; PV: O^T[d,q] += Vt x P^T
#pragma unroll
    for (int sub = 0; sub < 2; sub++) {
      const int kc = kt * 2 + sub;
      unsigned a0 = pw[sub * 4 + 0], a1 = pw[sub * 4 + 1];
      unsigned a2 = pw[sub * 4 + 2], a3 = pw[sub * 4 + 3];
      union { unsigned u[4]; hf8 v; } pu;
#if __has_builtin(__builtin_amdgcn_permlane32_swap)
      uint2_t r02 = __builtin_amdgcn_permlane32_swap(a0, a2, false, false);
      uint2_t r13 = __builtin_amdgcn_permlane32_swap(a1, a3, false, false);
      pu.u[0] = r02[0];  // {a0.lo, a2.lo}: keys base+{0,1}
      pu.u[1] = r13[0];  //                      +{2,3}
      pu.u[2] = r02[1];  // {a0.hi, a2.hi}: keys base+{4,5}
      pu.u[3] = r13[1];  //                      +{6,7}
#else
      const int hh_ = (threadIdx.x & 63) >> 5;
      unsigned x0 = __shfl_xor(a0, 32, 64), x1 = __shfl_xor(a1, 32, 64);
      unsigned x2 = __shfl_xor(a2, 32, 64), x3 = __shfl_xor(a3, 32, 64);
      pu.u[0] = hh_ ? x2 : a0;
      pu.u[1] = hh_ ? x3 : a1;
      pu.u[2] = hh_ ? a2 : x0;
      pu.u[3] = hh_ ? a3 : x1;
#endif
      __builtin_amdgcn_s_setprio(1);
#pragma unroll
      for (int dt = 0; dt < 2; dt++) {
        hf8 vf =
            *(const hf8*)(base + kofs[kc] + 16384 + CUR * 8192 + dt * 4096);
        ot[dt] =
            __builtin_amdgcn_mfma_f32_32x32x16_f16(vf, pu.v, ot[dt], 0, 0, 0);
      }
      __builtin_amdgcn_s_setprio(0);
    }
  }
  __syncthreads();
}

__global__ __launch_bounds__(512, 4) void attn_kernel(
    const half_t* __restrict__ Qh, const half_t* __restrict__ Kh,
    const half_t* __restrict__ Vth, half_t* __restrict__ ah) {
  __shared__ __align__(16) char smem[65536];
  const int tid = threadIdx.x, wid = tid >> 6, lane = tid & 63;
  const int l31 = lane & 31, hh = lane >> 5;
  const int qw = wid & 3, g = wid >> 2;
  // XCD swizzle: 512 blocks, xcd = lin%8 owns bh in [xcd*4, xcd*4+4) (16 blocks/bh)
  const int lin = blockIdx.x;
  const int slot = lin >> 3;
  const int bh = (lin & 7) * 4 + (slot >> 4);  // b*16 + h
  const int qb = slot & 15;
  const int b = bh >> 4, hd = bh & 15;
  const int t = qb * 128 + qw * 32 + l31;  // this lane's q-row (MFMA col)

  char* base = smem + g * 32768;  // K: [2][8192B], V at +16384: [2][8192B]

  const half_t* qrow = Qh + ((size_t)bh * 2048 + t) * 64;
  hf8 qf[4];
#pragma unroll
  for (int kc = 0; kc < 4; kc++) qf[kc] = *(const hf8*)(qrow + kc * 16 + hh * 8);

  f32x16 ot[2];
#pragma unroll
  for (int dt = 0; dt < 2; dt++)
#pragma unroll
    for (int i = 0; i < 16; i++) ot[dt][i] = 0.f;
  f32x16 zv;
#pragma unroll
  for (int i = 0; i < 16; i++) zv[i] = 0.f;
  float psAcc = 0.f;
  const hf2 ones = {(_Float16)1.0f, (_Float16)1.0f};

  const half_t* Kb = Kh + (size_t)bh * 2048 * 64;
  const half_t* Vb = Vth + (size_t)bh * 64 * 2048;
  const int kvbase = g * 1024;

  // hoisted LDS read offsets (bytes); kt/dt/cur/V are immediates
  int kofs[4];
#pragma unroll
  for (int kc = 0; kc < 4; kc++)
    kofs[kc] = l31 * 128 + ((kc * 32 + hh * 16) ^ ((l31 & 7) << 4));

  // advancing global element offsets (K: +4096/tile, V: +64/tile)
  int gk0, gk1, gv0, gv1;
  {
    int c0 = qw * 64 + lane, c1 = 256 + qw * 64 + lane;
    int r0 = c0 >> 3, s0 = (c0 & 7) ^ (r0 & 7);
    int r1 = c1 >> 3, s1 = (c1 & 7) ^ (r1 & 7);
    gk0 = (kvbase + r0) * 64 + s0 * 8;
    gk1 = (kvbase + r1) * 64 + s1 * 8;
    gv0 = r0 * 2048 + kvbase + s0 * 8;
    gv1 = r1 * 2048 + kvbase + s1 * 8;
  }
  // prologue: stage tile 0 into buf 0
  gload16(Kb + gk0, base + qw * 1024);
  gload16(Kb + gk1, base + 4096 + qw * 1024);
  gload16(Vb + gv0, base + 16384 + qw * 1024);
  gload16(Vb + gv1, base + 16384 + 4096 + qw * 1024);
  gk0 += 4096;
  gk1 += 4096;
  gv0 += 64;
  gv1 += 64;
  __syncthreads();

  for (int tp = 0; tp < 8; ++tp) {
    attn_tile_t<0>(true, Kb, Vb, base, qw, gk0, gk1, gv0, gv1, kofs, qf, zv,
                   ot, psAcc, ones);
    attn_tile_t<1>(tp < 7, Kb, Vb, base, qw, gk0, gk1, gv0, gv1, kofs, qf, zv,
                   ot, psAcc, ones);
  }

  const float lrun = psAcc + __shfl_xor(psAcc, 32, 64);

  // combine the two kv-groups' partial O / l via LDS (smem reusable after barrier)
  float* cb = (float*)smem;            // [4][2][16][64] f32 = 32KB
  float* lb = (float*)(smem + 32768);  // [4][64]
  if (g == 1) {
#pragma unroll
    for (int dt = 0; dt < 2; dt++)
#pragma unroll
      for (int i = 0; i < 16; i++)
        cb[((qw * 2 + dt) * 16 + i) * 64 + lane] = ot[dt][i];
    lb[qw * 64 + lane] = lrun;
  }
  __syncthreads();
  if (g == 0) {
#pragma unroll
    for (int dt = 0; dt < 2; dt++)
#pragma unroll
      for (int i = 0; i < 16; i++)
        ot[dt][i] += cb[((qw * 2 + dt) * 16 + i) * 64 + lane];
    const float inv = 1.0f / (lrun + lb[qw * 64 + lane]);
    const size_t obase = ((size_t)b * 2048 + t) * 1024 + hd * 64;
#pragma unroll
    for (int dt = 0; dt < 2; dt++)
#pragma unroll
      for (int gg = 0; gg < 4; gg++) {
        hf4 pk;
#pragma unroll
        for (int i2 = 0; i2 < 4; i2++)
          pk[i2] = (half_t)(ot[dt][4 * gg + i2] * inv);
        *(hf4*)(ah + obase + dt * 32 + 8 * gg + 4 * hh) = pk;
      }
  }
}

// ---------------- output projection: out = attn @ Wo^T + bo (f32 out) ----------------
__global__ __launch_bounds__(256, 3) void outproj_kernel(
    const half_t* __restrict__ ah, const half_t* __restrict__ woh,
    const float* __restrict__ bo, float* __restrict__ out) {
  __shared__ __align__(16) char ldsb[49152];
  const int m0 = blockIdx.x * 128, n0 = blockIdx.y * 64;
  f32x16 acc[2];
  gemm_core(ah, woh, m0, n0, ldsb, acc);
  const int tid = threadIdx.x, wid = tid >> 6, lane = tid & 63;
  const int l31 = lane & 31, hh = lane >> 5;
  const int wm = wid >> 1, wn = wid & 1;
  const int n = n0 + wn * 32 + l31;
  const float bsv = bo[n];
#pragma unroll
  for (int mt = 0; mt < 2; mt++) {
    const int mbase = m0 + wm * 64 + mt * 32;
#pragma unroll
    for (int r = 0; r < 16; r++) {
      const int m = mbase + (r & 3) + 8 * (r >> 2) + 4 * hh;
      out[(size_t)m * 1024 + n] = acc[mt][r] + bsv;
    }
  }
}

extern "C" void kernel_launch(void* const* d_in, const int* in_sizes, int n_in,
                              void* d_out, int out_size, void* d_ws,
                              size_t ws_size, hipStream_t stream) {
  const float* x = (const float*)d_in[0];
  const float* Wq = (const float*)d_in[1];
  const float* bq = (const float*)d_in[2];
  const float* Wk = (const float*)d_in[3];
  const float* bk = (const float*)d_in[4];
  const float* Wv = (const float*)d_in[5];
  const float* bv = (const float*)d_in[6];
  const float* Wo = (const float*)d_in[7];
  const float* bo = (const float*)d_in[8];
  const float* qr = (const float*)d_in[9];
  const float* qi = (const float*)d_in[10];
  const float* kr = (const float*)d_in[11];
  const float* ki = (const float*)d_in[12];
  float* out = (float*)d_out;

  char* ws = (char*)d_ws;
  half_t* xh = (half_t*)(ws);                  // 4194304 f16
  half_t* wh = (half_t*)(ws + 8388608);        // 4 x 1048576 f16 (Wq,Wk,Wv,Wo)
  half_t* Qh = (half_t*)(ws + 16777216);       // [B,H,T,64]
  half_t* Kh = (half_t*)(ws + 25165824);       // [B,H,T,64]
  half_t* Vth = (half_t*)(ws + 33554432);      // [B,H,64,T]
  half_t* ah = (half_t*)(ws + 41943040);       // [B,T,D]

  cvt_kernel<<<dim3(2048), dim3(256), 0, stream>>>(x, Wq, Wk, Wv, Wo, xh, wh);
  proj_kernel<<<dim3(32, 16, 3), dim3(256), 0, stream>>>(
      xh, wh, bq, bk, bv, qr, qi, kr, ki, Qh, Kh, Vth);
  attn_kernel<<<dim3(512), dim3(512), 0, stream>>>(Qh, Kh, Vth, ah);
  outproj_kernel<<<dim3(32, 16), dim3(256), 0, stream>>>(ah, wh + 3 * 1048576,
                                                         bo, out);
}